// Round 2
// baseline (144.530 us; speedup 1.0000x reference)
//
#include <hip/hip_runtime.h>
#include <math.h>

// Symmetry_Set_Basis: out[b,n] = q[b,n]*A_b + D_b
//   f_b[7] from power sums of v[b,:] (Newton's identities + signed roots)
//   ke = f @ wk_w + wk_b   (constant over set axis)
//   kn_j = ke_j/(sqrt(N)|ke_j|+1e-10)
//   nq_j = sqrt(w_j^2*S2q + 2 w_j b_j S1q + N b_j^2)+1e-10
//   A = sum_j kn_j*f_j*w_j/nq_j ; D = sum_j kn_j*f_j*b_j/nq_j

constexpr int NTH = 256;   // threads per block (one block per row)
constexpr int NN  = 4096;  // set size (row length)

__global__ __launch_bounds__(NTH) void symm_set_basis_kernel(
    const float* __restrict__ q,
    const float* __restrict__ v,
    const float* __restrict__ wq_w,   // [1,7]
    const float* __restrict__ wq_b,   // [7]
    const float* __restrict__ wk_w,   // [7,7] row-major
    const float* __restrict__ wk_b,   // [7]
    float* __restrict__ out)
{
    const int b = blockIdx.x;
    const int t = threadIdx.x;
    const float4* q4 = (const float4*)(q + (size_t)b * NN);
    const float4* v4 = (const float4*)(v + (size_t)b * NN);
    float4*       o4 = (float4*)(out + (size_t)b * NN);

    // coalesced float4 loads; keep q in registers for the final write
    float4 qv[4], vv[4];
    #pragma unroll
    for (int i = 0; i < 4; ++i) {
        qv[i] = q4[t + i * NTH];
        vv[i] = v4[t + i * NTH];
    }

    // per-thread partial sums in f32 (16 terms each -> negligible rounding)
    float p1 = 0.f, p2 = 0.f, p3 = 0.f, p4 = 0.f, s1 = 0.f, s2 = 0.f;
    #pragma unroll
    for (int i = 0; i < 4; ++i) {
        const float xs[4] = {vv[i].x, vv[i].y, vv[i].z, vv[i].w};
        const float qs[4] = {qv[i].x, qv[i].y, qv[i].z, qv[i].w};
        #pragma unroll
        for (int j = 0; j < 4; ++j) {
            const float x  = xs[j];
            const float x2 = x * x;
            p1 += x;
            p2 += x2;
            p3 += x2 * x;
            p4 += x2 * x2;
            const float qq = qs[j];
            s1 += qq;
            s2 += qq * qq;
        }
    }

    // cross-lane reduce in f64 (wave64), then cross-wave via LDS
    double r[6] = {(double)p1, (double)p2, (double)p3, (double)p4,
                   (double)s1, (double)s2};
    #pragma unroll
    for (int off = 32; off > 0; off >>= 1) {
        #pragma unroll
        for (int k = 0; k < 6; ++k) r[k] += __shfl_down(r[k], off, 64);
    }

    __shared__ double red[4][6];
    const int wave = t >> 6, lane = t & 63;
    if (lane == 0) {
        #pragma unroll
        for (int k = 0; k < 6; ++k) red[wave][k] = r[k];
    }
    __syncthreads();

    double tot[6];
    #pragma unroll
    for (int k = 0; k < 6; ++k)
        tot[k] = red[0][k] + red[1][k] + red[2][k] + red[3][k];

    const double P1 = tot[0], P2 = tot[1], P3 = tot[2], P4 = tot[3];
    const double S1 = tot[4], S2 = tot[5];

    // Newton's identities -> elementary symmetric polynomials
    const double e1 = P1;
    const double e2 = (P1 * P1 - P2) * 0.5;
    const double e3 = (P1 * P1 * P1 - P3 - 3.0 * (P2 * P1 - P3)) / 6.0;
    const double e4 = (e3 * P1 - e2 * P2 + e1 * P3 - P4) * 0.25;

    auto sroot = [](double x, double rr) {
        return copysign(pow(fabs(x), 1.0 / rr), x);
    };
    double f[7];
    f[0] = e1;
    f[1] = sroot(e2, 2.0);
    f[2] = sroot(e3, 3.0);
    f[3] = sroot(e4, 4.0);
    f[4] = sroot(P2, 2.0);
    f[5] = sroot(P3, 3.0);
    f[6] = sroot(P4, 4.0);

    // ke = f @ wk_w + wk_b  (7x7, scalar; weights are L1/L2-resident)
    double ke[7];
    #pragma unroll
    for (int j = 0; j < 7; ++j) {
        double acc = (double)wk_b[j];
        #pragma unroll
        for (int i = 0; i < 7; ++i) acc += f[i] * (double)wk_w[i * 7 + j];
        ke[j] = acc;
    }

    const double sqrtN = sqrt((double)NN);
    double A = 0.0, D = 0.0;
    #pragma unroll
    for (int j = 0; j < 7; ++j) {
        const double wj  = (double)wq_w[j];
        const double bj  = (double)wq_b[j];
        const double knj = ke[j] / (sqrtN * fabs(ke[j]) + 1e-10);
        const double nq  = sqrt(wj * wj * S2 + 2.0 * wj * bj * S1 +
                                (double)NN * bj * bj) + 1e-10;
        const double g = knj * f[j] / nq;
        A += g * wj;
        D += g * bj;
    }
    const float Af = (float)A, Df = (float)D;

    // out = q*A + D, coalesced float4 stores
    #pragma unroll
    for (int i = 0; i < 4; ++i) {
        float4 o;
        o.x = qv[i].x * Af + Df;
        o.y = qv[i].y * Af + Df;
        o.z = qv[i].z * Af + Df;
        o.w = qv[i].w * Af + Df;
        o4[t + i * NTH] = o;
    }
}

extern "C" void kernel_launch(void* const* d_in, const int* in_sizes, int n_in,
                              void* d_out, int out_size, void* d_ws, size_t ws_size,
                              hipStream_t stream) {
    const float* q    = (const float*)d_in[0];
    // d_in[1] (k) is unused by the layer
    const float* v    = (const float*)d_in[2];
    const float* wq_w = (const float*)d_in[3];
    const float* wq_b = (const float*)d_in[4];
    const float* wk_w = (const float*)d_in[5];
    const float* wk_b = (const float*)d_in[6];
    float* out = (float*)d_out;

    const int B = in_sizes[0] / NN;  // 2048
    symm_set_basis_kernel<<<B, NTH, 0, stream>>>(q, v, wq_w, wq_b, wk_w, wk_b, out);
}

// Round 5
// 135.900 us; speedup vs baseline: 1.0635x; 1.0635x over previous
//
#include <hip/hip_runtime.h>
#include <math.h>

// Symmetry_Set_Basis: out[b,n] = q[b,n]*A_b + D_b
//   f_b[7] from power sums of v[b,:] (Newton's identities + signed roots)
//   ke = f @ wk_w + wk_b  (constant over set axis) -> kn_j = ke_j/(sqrt(N)|ke_j|+1e-10)
//   nq_j = sqrt(w_j^2*S2q + 2 w_j b_j S1q + N b_j^2)+1e-10
//   A = sum_j kn_j*f_j*w_j/nq_j ; D = sum_j kn_j*f_j*b_j/nq_j
//
// R2 -> R3: epilogue on wave 0 only (was: all 4 waves redundantly);
// pow() replaced by HW sqrt_f64 / sqrt(sqrt) / f32-seeded Newton cbrt.

constexpr int NTH = 256;   // threads per block (one block per row)
constexpr int NN  = 4096;  // set size (row length)

__device__ inline double sroot2(double x) {
    return copysign(sqrt(fabs(x)), x);
}
__device__ inline double sroot4(double x) {
    return copysign(sqrt(sqrt(fabs(x))), x);
}
__device__ inline double sroot3(double x) {
    double a = fabs(x);
    if (a < 1e-300) return 0.0;
    // f32 seed via HW exp2/log2 (~1e-6 rel), two f64 Newton steps -> full f64
    double y = (double)exp2f(log2f((float)a) * (1.0f / 3.0f));
    y = (2.0 * y + a / (y * y)) * (1.0 / 3.0);
    y = (2.0 * y + a / (y * y)) * (1.0 / 3.0);
    return copysign(y, x);
}

__global__ __launch_bounds__(NTH) void symm_set_basis_kernel(
    const float* __restrict__ q,
    const float* __restrict__ v,
    const float* __restrict__ wq_w,   // [1,7]
    const float* __restrict__ wq_b,   // [7]
    const float* __restrict__ wk_w,   // [7,7] row-major
    const float* __restrict__ wk_b,   // [7]
    float* __restrict__ out)
{
    const int b = blockIdx.x;
    const int t = threadIdx.x;
    const float4* q4 = (const float4*)(q + (size_t)b * NN);
    const float4* v4 = (const float4*)(v + (size_t)b * NN);
    float4*       o4 = (float4*)(out + (size_t)b * NN);

    // coalesced float4 loads; keep q in registers for the final write
    float4 qv[4], vv[4];
    #pragma unroll
    for (int i = 0; i < 4; ++i) {
        qv[i] = q4[t + i * NTH];
        vv[i] = v4[t + i * NTH];
    }

    // per-thread partial sums in f32 (16 terms each -> negligible rounding)
    float p1 = 0.f, p2 = 0.f, p3 = 0.f, p4 = 0.f, s1 = 0.f, s2 = 0.f;
    #pragma unroll
    for (int i = 0; i < 4; ++i) {
        const float xs[4] = {vv[i].x, vv[i].y, vv[i].z, vv[i].w};
        const float qs[4] = {qv[i].x, qv[i].y, qv[i].z, qv[i].w};
        #pragma unroll
        for (int j = 0; j < 4; ++j) {
            const float x  = xs[j];
            const float x2 = x * x;
            p1 += x;
            p2 += x2;
            p3 += x2 * x;
            p4 += x2 * x2;
            const float qq = qs[j];
            s1 += qq;
            s2 += qq * qq;
        }
    }

    // cross-lane butterfly in f64 (wave64), then wave partials via LDS
    double r[6] = {(double)p1, (double)p2, (double)p3, (double)p4,
                   (double)s1, (double)s2};
    #pragma unroll
    for (int off = 32; off > 0; off >>= 1) {
        #pragma unroll
        for (int k = 0; k < 6; ++k) r[k] += __shfl_down(r[k], off, 64);
    }

    __shared__ double red[4][6];
    __shared__ float  AD[2];
    const int wave = t >> 6, lane = t & 63;
    if (lane == 0) {
        #pragma unroll
        for (int k = 0; k < 6; ++k) red[wave][k] = r[k];
    }
    __syncthreads();

    if (wave == 0) {
        // epilogue: redundant across wave 0's lanes only
        double tot[6];
        #pragma unroll
        for (int k = 0; k < 6; ++k)
            tot[k] = red[0][k] + red[1][k] + red[2][k] + red[3][k];

        const double P1 = tot[0], P2 = tot[1], P3 = tot[2], P4 = tot[3];
        const double S1 = tot[4], S2 = tot[5];

        // Newton's identities -> elementary symmetric polynomials
        const double e1 = P1;
        const double e2 = (P1 * P1 - P2) * 0.5;
        const double e3 = (P1 * P1 * P1 - P3 - 3.0 * (P2 * P1 - P3)) / 6.0;
        const double e4 = (e3 * P1 - e2 * P2 + e1 * P3 - P4) * 0.25;

        double f[7];
        f[0] = e1;
        f[1] = sroot2(e2);
        f[2] = sroot3(e3);
        f[3] = sroot4(e4);
        f[4] = sroot2(P2);
        f[5] = sroot3(P3);
        f[6] = sroot4(P4);

        // ke = f @ wk_w + wk_b (7x7 scalar; weights L2-resident)
        double ke[7];
        #pragma unroll
        for (int j = 0; j < 7; ++j) {
            double acc = (double)wk_b[j];
            #pragma unroll
            for (int i = 0; i < 7; ++i) acc += f[i] * (double)wk_w[i * 7 + j];
            ke[j] = acc;
        }

        const double sqrtN = sqrt((double)NN);
        double A = 0.0, D = 0.0;
        #pragma unroll
        for (int j = 0; j < 7; ++j) {
            const double wj  = (double)wq_w[j];
            const double bj  = (double)wq_b[j];
            const double knj = ke[j] / (sqrtN * fabs(ke[j]) + 1e-10);
            const double nq  = sqrt(wj * wj * S2 + 2.0 * wj * bj * S1 +
                                    (double)NN * bj * bj) + 1e-10;
            const double g = knj * f[j] / nq;
            A += g * wj;
            D += g * bj;
        }
        if (lane == 0) {
            AD[0] = (float)A;
            AD[1] = (float)D;
        }
    }
    __syncthreads();

    const float Af = AD[0], Df = AD[1];

    // out = q*A + D, coalesced float4 stores
    #pragma unroll
    for (int i = 0; i < 4; ++i) {
        float4 o;
        o.x = qv[i].x * Af + Df;
        o.y = qv[i].y * Af + Df;
        o.z = qv[i].z * Af + Df;
        o.w = qv[i].w * Af + Df;
        o4[t + i * NTH] = o;
    }
}

extern "C" void kernel_launch(void* const* d_in, const int* in_sizes, int n_in,
                              void* d_out, int out_size, void* d_ws, size_t ws_size,
                              hipStream_t stream) {
    const float* q    = (const float*)d_in[0];
    // d_in[1] (k) is unused by the layer
    const float* v    = (const float*)d_in[2];
    const float* wq_w = (const float*)d_in[3];
    const float* wq_b = (const float*)d_in[4];
    const float* wk_w = (const float*)d_in[5];
    const float* wk_b = (const float*)d_in[6];
    float* out = (float*)d_out;

    const int B = in_sizes[0] / NN;  // 2048
    symm_set_basis_kernel<<<B, NTH, 0, stream>>>(q, v, wq_w, wq_b, wk_w, wk_b, out);
}